// Round 7
// baseline (238.916 us; speedup 1.0000x reference)
//
#include <hip/hip_runtime.h>
#include <hip/hip_bf16.h>
#include <math.h>

typedef short short8_t __attribute__((ext_vector_type(8)));
typedef float floatx4  __attribute__((ext_vector_type(4)));
typedef float floatx2  __attribute__((ext_vector_type(2)));
typedef unsigned int uint;

#define EPB 1024   // edges per scatter block
#define BSH 9      // 512 nodes per coarse bucket
#define CAP 8192   // fixed edge capacity per bucket region (max bucket ~5400)

// ---------------- bf16 helpers (RNE) ----------------------------------------

__device__ inline unsigned short f2b(float f) {
    uint u = __float_as_uint(f);
    u += 0x7fff + ((u >> 16) & 1);
    return (unsigned short)(u >> 16);
}
__device__ inline uint pack2(float a, float b) {
    return (uint)f2b(a) | ((uint)f2b(b) << 16);
}

// ---------------- fp8 (e4m3) helpers -----------------------------------------

__device__ inline uint enc4_fp8(float f0, float f1, float f2, float f3) {
    uint v = __builtin_amdgcn_cvt_pk_fp8_f32(f0, f1, 0, false);
    v = __builtin_amdgcn_cvt_pk_fp8_f32(f2, f3, v, true);
    return v;
}
__device__ inline unsigned char enc1_fp8(float f) {
    return (unsigned char)(__builtin_amdgcn_cvt_pk_fp8_f32(f, f, 0, false) & 0xff);
}

// Lesson ledger:
//  R10/R13: GLOBAL atomic histogram (1 atomic/edge) pinned ~43-50us. LDS hist
//       + few global atomics per block is the pattern that works.
//  R12: co-scheduling light branches in one grid is free.
//  R11/R14/R15: a latency-bound phase inherits a fused kernel's worst-phase
//       occupancy — per-BLOCK fusion of gather into MFMA collapsed (139us).
//  R9: keep scatter targets packed (L2-resident).
//  R17 (FAILED): coop grid.sync costs ~350us EACH on 8-XCD gfx950. Never.
//  R18 (FAILED): device-scope fences/tickets per block are mini grid.syncs.
//  R19: full-tile single-barrier linear staging — keep. Exposed gather2.
//  R20: gathers -> 1 node per lane-group (no shfl reduce, lane-parallel
//       epilogue): 256 -> 230us. Model: ~85us work + ~15us PER DISPATCH
//       (boundary sched + dirty-L2 writeback).
//  R21 (this round): kill k_scan_bh via fixed-capacity bucket regions
//       (CAP=8192): scatter gets bases from per-bucket cursor atomicAdd
//       (seeded k*CAP in phase A), bucket_csr derives count from cursor,
//       writes deg[] so gathers need no cross-bucket sentinel. Phase A's
//       hist branch gone. 9 -> 8 dispatches.

// ---------------- phase A: cvt_x | cvt_w | zero(pooled) | cursors | gstart ----

__global__ __launch_bounds__(256) void k_phase_a(
    const float* __restrict__ x, unsigned short* __restrict__ xb,
    unsigned char* __restrict__ xf8, int nX,
    const float* __restrict__ Wl1, const float* __restrict__ Wr1,
    const float* __restrict__ Wl2, const float* __restrict__ Wr2,
    unsigned short* __restrict__ wbuf,
    float* __restrict__ pooled, int* __restrict__ cursor,
    const int* __restrict__ batch, int* __restrict__ gstart, int N, int G,
    int bCvtX, int bCvtW, int bZero) {
    int b = blockIdx.x;
    int tid = threadIdx.x;
    if (b < bCvtX) {
        int i = (b * 256 + tid) * 8;
        if (i < nX) {
            float4 v0 = *(const float4*)(x + i);
            float4 v1 = *(const float4*)(x + i + 4);
            uint4 ob;
            ob.x = pack2(v0.x, v0.y);
            ob.y = pack2(v0.z, v0.w);
            ob.z = pack2(v1.x, v1.y);
            ob.w = pack2(v1.z, v1.w);
            *(uint4*)(xb + i) = ob;
            uint2 of;
            of.x = enc4_fp8(v0.x, v0.y, v0.z, v0.w);
            of.y = enc4_fp8(v1.x, v1.y, v1.z, v1.w);
            *(uint2*)(xf8 + i) = of;
        }
    } else if (b < bCvtX + bCvtW) {
        int i = (b - bCvtX) * 256 + tid;
        if (i < 49152) {
            float v;
            if (i < 8192)       v = Wl1[i];
            else if (i < 16384) v = Wr1[i - 8192];
            else if (i < 32768) v = Wl2[i - 16384];
            else                v = Wr2[i - 32768];
            wbuf[i] = f2b(v);
        }
    } else if (b < bCvtX + bCvtW + bZero) {
        // zero pooled[256][128] (32768 floats) — consumed by linear2 atomics
        int i = ((b - bCvtX - bCvtW) * 256 + tid) * 4;
        float4 z = make_float4(0.f, 0.f, 0.f, 0.f);
        *(float4*)(pooled + i) = z;
    } else if (b == bCvtX + bCvtW + bZero) {
        // seed per-bucket cursors to region bases
        cursor[tid] = tid * CAP;
    } else {
        for (int g = tid; g <= G; g += 256) {
            if (g == G) { gstart[G] = N; continue; }
            int lo = 0, hi = N;
            while (lo < hi) {
                int mid = (lo + hi) >> 1;
                if (batch[mid] < g) lo = mid + 1; else hi = mid;
            }
            gstart[g] = lo;
        }
    }
}

// ---------------- scatter: LDS hist -> cursor atomics -> bucketed ebuf --------
// record = (dst&511)<<23 | src   (requires src < 2^23)

__global__ __launch_bounds__(256) void k_scatter(
    const int* __restrict__ src, const int* __restrict__ dst,
    int* __restrict__ cursor, int* __restrict__ ebuf, int E) {
    __shared__ int h[256];
    int b = blockIdx.x;
    int t = threadIdx.x;
    h[t] = 0;
    __syncthreads();
    int e0 = b * EPB + t * 4;
    int4 d4, s4;
    bool full = (e0 + 3 < E);
    if (full) {
        d4 = *(const int4*)(dst + e0);
        s4 = *(const int4*)(src + e0);
        atomicAdd(&h[d4.x >> BSH], 1);
        atomicAdd(&h[d4.y >> BSH], 1);
        atomicAdd(&h[d4.z >> BSH], 1);
        atomicAdd(&h[d4.w >> BSH], 1);
    } else {
        for (int q = e0; q < E; ++q) atomicAdd(&h[dst[q] >> BSH], 1);
    }
    __syncthreads();
    int c = h[t];
    __syncthreads();
    h[t] = (c > 0) ? atomicAdd(&cursor[t], c) : 0;
    __syncthreads();
    if (full) {
        int k, p;
        k = d4.x >> BSH; p = atomicAdd(&h[k], 1); if (p < (k + 1) * CAP) ebuf[p] = ((d4.x & 511) << 23) | s4.x;
        k = d4.y >> BSH; p = atomicAdd(&h[k], 1); if (p < (k + 1) * CAP) ebuf[p] = ((d4.y & 511) << 23) | s4.y;
        k = d4.z >> BSH; p = atomicAdd(&h[k], 1); if (p < (k + 1) * CAP) ebuf[p] = ((d4.z & 511) << 23) | s4.z;
        k = d4.w >> BSH; p = atomicAdd(&h[k], 1); if (p < (k + 1) * CAP) ebuf[p] = ((d4.w & 511) << 23) | s4.w;
    } else {
        for (int q = e0; q < E; ++q) {
            int d = dst[q];
            int k = d >> BSH;
            int p = atomicAdd(&h[k], 1);
            if (p < (k + 1) * CAP) ebuf[p] = ((d & 511) << 23) | src[q];
        }
    }
}

// ---------------- per-bucket counting sort -> row_start + deg + csr_src ------

__global__ __launch_bounds__(256) void k_bucket_csr(
    const int* __restrict__ ebuf, const int* __restrict__ cursor,
    int* __restrict__ row_start, int* __restrict__ deg,
    int* __restrict__ csr_src, int N) {
    __shared__ int ss[256];
    __shared__ int h2[512];
    int k = blockIdx.x;
    int t = threadIdx.x;
    int B = k * CAP;
    int ck = cursor[k] - B;
    if (ck > CAP) ck = CAP;
    int node0 = k << BSH;
    int nn = N - node0; if (nn > 512) nn = 512;
    h2[t] = 0; h2[t + 256] = 0;
    __syncthreads();
    for (int i = B + t; i < B + ck; i += 256)
        atomicAdd(&h2[((uint)ebuf[i]) >> 23], 1);
    __syncthreads();
    int a0 = h2[2 * t], a1 = h2[2 * t + 1];
    // per-node degrees (needed by gathers: e = row_start[n] + deg[n])
    if (2 * t < nn)     deg[node0 + 2 * t]     = a0;
    if (2 * t + 1 < nn) deg[node0 + 2 * t + 1] = a1;
    int ps = a0 + a1;
    ss[t] = ps;
    __syncthreads();
#pragma unroll
    for (int off = 1; off < 256; off <<= 1) {
        int u = (t >= off) ? ss[t - off] : 0;
        __syncthreads();
        ss[t] += u;
        __syncthreads();
    }
    int base = ss[t] - ps;
    h2[2 * t] = base;
    h2[2 * t + 1] = base + a0;
    __syncthreads();
    int rs0 = h2[t];
    int rs1 = h2[t + 256];
    __syncthreads();
    if (t < nn)       row_start[node0 + t]       = B + rs0;
    if (t + 256 < nn) row_start[node0 + t + 256] = B + rs1;
    for (int i = B + t; i < B + ck; i += 256) {
        int rec = ebuf[i];
        int j = ((uint)rec) >> 23;
        int pos = atomicAdd(&h2[j], 1);
        csr_src[B + pos] = rec & 0x7FFFFF;
    }
}

// ---------------- mean aggregation (fp8 in, bf16 out, fp32 accumulate) -------
// R20: 1 node per LANE-GROUP: no cross-lane reduce, every lane packs/stores
// its own 8 outputs. Serial edge loop, 2-deep unroll for MLP.

#define ACCF8(v)                                                        \
    { floatx2 f = __builtin_amdgcn_cvt_pk_f32_fp8((v).x, false);        \
      a[0] += f[0]; a[1] += f[1];                                       \
      f = __builtin_amdgcn_cvt_pk_f32_fp8((v).x, true);                 \
      a[2] += f[0]; a[3] += f[1];                                       \
      f = __builtin_amdgcn_cvt_pk_f32_fp8((v).y, false);                \
      a[4] += f[0]; a[5] += f[1];                                       \
      f = __builtin_amdgcn_cvt_pk_f32_fp8((v).y, true);                 \
      a[6] += f[0]; a[7] += f[1]; }

// K=64: 8 lanes per node (8B each), 32 nodes per 256-thread block.
__global__ void k_gather1(const unsigned char* __restrict__ xf8,
                          const int* __restrict__ row_start,
                          const int* __restrict__ deg,
                          const int* __restrict__ csr_src,
                          unsigned short* __restrict__ agg, int n_nodes) {
    int tid = threadIdx.x;
    int node = blockIdx.x * 32 + (tid >> 3);
    if (node >= n_nodes) return;
    int lp = tid & 7;
    int s = row_start[node];
    int d = deg[node];
    int e = s + d;
    float a[8];
#pragma unroll
    for (int q = 0; q < 8; ++q) a[q] = 0.f;
    int i = s;
    for (; i + 1 < e; i += 2) {
        int u0 = csr_src[i];
        int u1 = csr_src[i + 1];
        uint2 v0 = *(const uint2*)(xf8 + (size_t)u0 * 64 + lp * 8);
        uint2 v1 = *(const uint2*)(xf8 + (size_t)u1 * 64 + lp * 8);
        ACCF8(v0);
        ACCF8(v1);
    }
    if (i < e) {
        int u0 = csr_src[i];
        uint2 v0 = *(const uint2*)(xf8 + (size_t)u0 * 64 + lp * 8);
        ACCF8(v0);
    }
    float scale = (d > 0) ? (1.f / (float)d) : 1.f;
    uint4 o;
    o.x = pack2(a[0] * scale, a[1] * scale);
    o.y = pack2(a[2] * scale, a[3] * scale);
    o.z = pack2(a[4] * scale, a[5] * scale);
    o.w = pack2(a[6] * scale, a[7] * scale);
    *(uint4*)(agg + (size_t)node * 64 + lp * 8) = o;
}

// K=128: 16 lanes per node (8B each), 16 nodes per 256-thread block.
__global__ void k_gather2(const unsigned char* __restrict__ h1f8,
                          const int* __restrict__ row_start,
                          const int* __restrict__ deg,
                          const int* __restrict__ csr_src,
                          unsigned short* __restrict__ agg, int n_nodes) {
    int tid = threadIdx.x;
    int node = blockIdx.x * 16 + (tid >> 4);
    if (node >= n_nodes) return;
    int lp = tid & 15;
    int s = row_start[node];
    int d = deg[node];
    int e = s + d;
    float a[8];
#pragma unroll
    for (int q = 0; q < 8; ++q) a[q] = 0.f;
    int i = s;
    for (; i + 1 < e; i += 2) {
        int u0 = csr_src[i];
        int u1 = csr_src[i + 1];
        uint2 v0 = *(const uint2*)(h1f8 + (size_t)u0 * 128 + lp * 8);
        uint2 v1 = *(const uint2*)(h1f8 + (size_t)u1 * 128 + lp * 8);
        ACCF8(v0);
        ACCF8(v1);
    }
    if (i < e) {
        int u0 = csr_src[i];
        uint2 v0 = *(const uint2*)(h1f8 + (size_t)u0 * 128 + lp * 8);
        ACCF8(v0);
    }
    float scale = (d > 0) ? (1.f / (float)d) : 1.f;
    uint4 o;
    o.x = pack2(a[0] * scale, a[1] * scale);
    o.y = pack2(a[2] * scale, a[3] * scale);
    o.z = pack2(a[4] * scale, a[5] * scale);
    o.w = pack2(a[6] * scale, a[7] * scale);
    *(uint4*)(agg + (size_t)node * 128 + lp * 8) = o;
}

// ---------------- MFMA SAGE linear: relu(agg@Wl.T + bl + xin@Wr.T) ----------
// FULL-TILE staging: both 128xK operands resident in LDS, ONE barrier, then
// the whole K-loop is sync-free MFMA+ds_read. Rows padded to K+8 shorts.
// POOL=false: emit bf16 h + fp8 copy. POOL=true: R2-validated epilogue —
// per-thread running per-graph sums + atomicAdd into pooled[G][128].

template <int K, bool POOL>
__global__ __launch_bounds__(256) void k_linear_mfma(
    const unsigned short* __restrict__ aggA, const unsigned short* __restrict__ xinA,
    const unsigned short* __restrict__ Wlb,  const float* __restrict__ bl,
    const unsigned short* __restrict__ Wrb,  unsigned short* __restrict__ out,
    unsigned char* __restrict__ outf8,
    const int* __restrict__ batch, float* __restrict__ pooled, int n_nodes) {
    constexpr int NCH = (2 * K) / 32;
    constexpr int KP = K + 8;              // padded row (shorts)
    constexpr int SLOTS = K / 8;           // uint4 slots per row
    __shared__ __align__(16) short As[2 * 128 * KP];
    __shared__ int bb[128];

    int tid  = threadIdx.x;
    int lane = tid & 63;
    int wave = tid >> 6;
    int quad = lane >> 4;
    int lr   = lane & 15;
    int node0 = blockIdx.x * 128;

    if (POOL && tid < 128) {
        int n = node0 + tid;
        bb[tid] = (n < n_nodes) ? batch[n] : 0;
    }

    // ---- stage both full tiles, all loads in flight, one barrier ------------
#pragma unroll
    for (int idx = tid; idx < 128 * SLOTS; idx += 256) {
        int row  = idx / SLOTS;
        int slot = idx % SLOTS;
        int n = node0 + row; if (n >= n_nodes) n = n_nodes - 1;
        uint4 va = *(const uint4*)(aggA + (size_t)n * K + slot * 8);
        uint4 vx = *(const uint4*)(xinA + (size_t)n * K + slot * 8);
        *(uint4*)(&As[row * KP + slot * 8]) = va;
        *(uint4*)(&As[128 * KP + row * KP + slot * 8]) = vx;
    }
    __syncthreads();

    floatx4 acc[8][2];
#pragma unroll
    for (int mi = 0; mi < 8; ++mi)
#pragma unroll
        for (int ni = 0; ni < 2; ++ni)
            acc[mi][ni] = (floatx4){0.f, 0.f, 0.f, 0.f};

#pragma unroll
    for (int c = 0; c < NCH; ++c) {
        const unsigned short* srcW = (c < K / 32) ? Wlb : Wrb;
        int base = (c < K / 32) ? 0 : 128 * KP;
        int kb   = (c < K / 32) ? c * 32 : (c - K / 32) * 32;

        short8_t bfrag[2];
#pragma unroll
        for (int ni = 0; ni < 2; ++ni) {
            int j = wave * 32 + ni * 16 + lr;
            bfrag[ni] = *(const short8_t*)(srcW + (size_t)j * K + kb + quad * 8);
        }
#pragma unroll
        for (int mi = 0; mi < 8; ++mi) {
            short8_t af = *(const short8_t*)(&As[base + (mi * 16 + lr) * KP + kb + quad * 8]);
            acc[mi][0] = __builtin_amdgcn_mfma_f32_16x16x32_bf16(af, bfrag[0], acc[mi][0], 0, 0, 0);
            acc[mi][1] = __builtin_amdgcn_mfma_f32_16x16x32_bf16(af, bfrag[1], acc[mi][1], 0, 0, 0);
        }
    }

    float b0 = bl[wave * 32 + lr];
    float b1 = bl[wave * 32 + 16 + lr];
    int j0 = wave * 32 + lr;

    if (!POOL) {
#pragma unroll
        for (int mi = 0; mi < 8; ++mi) {
#pragma unroll
            for (int r = 0; r < 4; ++r) {
                int node = node0 + mi * 16 + quad * 4 + r;
                if (node < n_nodes) {
                    float v0 = fmaxf(acc[mi][0][r] + b0, 0.f);
                    float v1 = fmaxf(acc[mi][1][r] + b1, 0.f);
                    out[(size_t)node * 128 + j0]      = f2b(v0);
                    out[(size_t)node * 128 + j0 + 16] = f2b(v1);
                    outf8[(size_t)node * 128 + j0]      = enc1_fp8(v0);
                    outf8[(size_t)node * 128 + j0 + 16] = enc1_fp8(v1);
                }
            }
        }
    } else {
        // R2-validated: thread's nodes are monotone -> running per-graph sums,
        // flush on boundary; ~1-2 graphs per 128-node window (batch sorted).
        int gcur = -1;
        float s0 = 0.f, s1 = 0.f;
#pragma unroll
        for (int mi = 0; mi < 8; ++mi) {
#pragma unroll
            for (int r = 0; r < 4; ++r) {
                int li = mi * 16 + quad * 4 + r;
                int node = node0 + li;
                if (node < n_nodes) {
                    float v0 = fmaxf(acc[mi][0][r] + b0, 0.f);
                    float v1 = fmaxf(acc[mi][1][r] + b1, 0.f);
                    int g = bb[li];
                    if (g != gcur) {
                        if (gcur >= 0) {
                            atomicAdd(&pooled[gcur * 128 + j0], s0);
                            atomicAdd(&pooled[gcur * 128 + j0 + 16], s1);
                        }
                        gcur = g; s0 = 0.f; s1 = 0.f;
                    }
                    s0 += v0;
                    s1 += v1;
                }
            }
        }
        if (gcur >= 0) {
            atomicAdd(&pooled[gcur * 128 + j0], s0);
            atomicAdd(&pooled[gcur * 128 + j0 + 16], s1);
        }
    }
}

// ---------------- tiny head: mean + linear + log_softmax ---------------------

__global__ void k_head(const float* __restrict__ pooled,
                       const int* __restrict__ gstart,
                       const float* __restrict__ Wout,
                       const float* __restrict__ bout,
                       float* __restrict__ out) {
    int g = blockIdx.x;
    int lane = threadIdx.x;  // 64
    float p0 = pooled[g * 128 + lane];
    float p1 = pooled[g * 128 + 64 + lane];
    float d0 = p0 * Wout[lane] + p1 * Wout[64 + lane];
    float d1 = p0 * Wout[128 + lane] + p1 * Wout[192 + lane];
#pragma unroll
    for (int m = 32; m > 0; m >>= 1) {
        d0 += __shfl_xor(d0, m);
        d1 += __shfl_xor(d1, m);
    }
    if (lane == 0) {
        float cnt = (float)(gstart[g + 1] - gstart[g]);
        float inv = (cnt > 0.f) ? (1.f / cnt) : 1.f;
        float l0 = d0 * inv + bout[0];
        float l1 = d1 * inv + bout[1];
        float mx = fmaxf(l0, l1);
        float lse = mx + logf(expf(l0 - mx) + expf(l1 - mx));
        out[g * 2 + 0] = l0 - lse;
        out[g * 2 + 1] = l1 - lse;
    }
}

// ---------------- launch -----------------------------------------------------

static inline size_t alignUp(size_t x, size_t a) { return (x + a - 1) & ~(a - 1); }

extern "C" void kernel_launch(void* const* d_in, const int* in_sizes, int n_in,
                              void* d_out, int out_size, void* d_ws, size_t ws_size,
                              hipStream_t stream) {
    const float* x    = (const float*)d_in[0];
    const int*   ei   = (const int*)d_in[1];
    const int*   batch= (const int*)d_in[2];
    const float* Wl1  = (const float*)d_in[3];
    const float* bl1  = (const float*)d_in[4];
    const float* Wr1  = (const float*)d_in[5];
    const float* Wl2  = (const float*)d_in[6];
    const float* bl2  = (const float*)d_in[7];
    const float* Wr2  = (const float*)d_in[8];
    const float* Wout = (const float*)d_in[9];
    const float* bout = (const float*)d_in[10];
    float* out = (float*)d_out;

    const int N = in_sizes[0] / 64;   // 100000 (must be < 2^23 for record packing)
    const int E = in_sizes[1] / 2;    // 1000000
    const int G = out_size / 2;       // 256

    const int* src = ei;
    const int* dst = ei + E;

    const int bScat = (E + EPB - 1) / EPB;     // 977
    const int NB    = (N + 511) >> BSH;        // 196 coarse buckets
    const int bCvtX = (N * 64 / 8 + 255) / 256;
    const int bCvtW = 192;
    const int bZero = (G * 128 / 4 + 255) / 256;    // 32

    // workspace layout
    char* ws = (char*)d_ws;
    size_t off = 0;
    int*   cursor    = (int*)(ws + off); off = alignUp(off + (size_t)256 * 4, 256);
    int*   row_start = (int*)(ws + off); off = alignUp(off + (size_t)N * 4, 256);
    int*   deg       = (int*)(ws + off); off = alignUp(off + (size_t)N * 4, 256);
    int*   ebuf      = (int*)(ws + off); off = alignUp(off + (size_t)256 * CAP * 4, 256);
    int*   csr_src   = (int*)(ws + off); off = alignUp(off + (size_t)256 * CAP * 4, 256);
    int*   gstart    = (int*)(ws + off); off = alignUp(off + (size_t)(G + 1) * 4, 256);
    unsigned short* xb   = (unsigned short*)(ws + off); off = alignUp(off + (size_t)N * 64 * 2, 256);
    unsigned char*  xf8  = (unsigned char*)(ws + off);  off = alignUp(off + (size_t)N * 64, 256);
    unsigned short* wbuf = (unsigned short*)(ws + off); off = alignUp(off + (size_t)49152 * 2, 256);
    unsigned short* agg1 = (unsigned short*)(ws + off); off = alignUp(off + (size_t)N * 64 * 2, 256);
    unsigned short* h1   = (unsigned short*)(ws + off); off = alignUp(off + (size_t)N * 128 * 2, 256);
    unsigned char*  h1f8 = (unsigned char*)(ws + off);  off = alignUp(off + (size_t)N * 128, 256);
    unsigned short* agg2 = (unsigned short*)(ws + off); off = alignUp(off + (size_t)N * 128 * 2, 256);
    float*          pooled = (float*)(ws + off); off = alignUp(off + (size_t)G * 128 * 4, 256);
    (void)ws_size;

    unsigned short* Wl1b = wbuf;
    unsigned short* Wr1b = wbuf + 8192;
    unsigned short* Wl2b = wbuf + 16384;
    unsigned short* Wr2b = wbuf + 32768;

    // phase A: cvt_x + cvt_w + zero(pooled) + cursor seed + graph bounds
    k_phase_a<<<bCvtX + bCvtW + bZero + 2, 256, 0, stream>>>(
        x, xb, xf8, N * 64,
        Wl1, Wr1, Wl2, Wr2, wbuf,
        pooled, cursor,
        batch, gstart, N, G,
        bCvtX, bCvtW, bZero);

    // scatter into fixed-capacity bucket regions + per-bucket counting sort
    k_scatter<<<bScat, 256, 0, stream>>>(src, dst, cursor, ebuf, E);
    k_bucket_csr<<<NB, 256, 0, stream>>>(ebuf, cursor, row_start, deg, csr_src, N);

    // layer 1: gather (fp8) -> MFMA linear (emits h1 bf16 + h1f8 fp8)
    k_gather1<<<(N + 31) / 32, 256, 0, stream>>>(xf8, row_start, deg, csr_src, agg1, N);
    k_linear_mfma<64, false><<<(N + 127) / 128, 256, 0, stream>>>(
        agg1, xb, Wl1b, bl1, Wr1b, h1, h1f8, nullptr, nullptr, N);

    // layer 2: gather -> MFMA linear + per-graph pool (fp32 atomics)
    k_gather2<<<(N + 15) / 16, 256, 0, stream>>>(h1f8, row_start, deg, csr_src, agg2, N);
    k_linear_mfma<128, true><<<(N + 127) / 128, 256, 0, stream>>>(
        agg2, h1, Wl2b, bl2, Wr2b, nullptr, nullptr, batch, pooled, N);

    // tiny head: mean + 128->2 linear + log_softmax
    k_head<<<G, 64, 0, stream>>>(pooled, gstart, Wout, bout, out);
}